// Round 9
// baseline (319.383 us; speedup 1.0000x reference)
//
#include <hip/hip_runtime.h>

#define NODES  30000
#define EDGES  480000
#define GRAPHS 500
#define MPAD   30016   // 64*469
#define NB     118     // scan blocks: ceil(30000/256)

typedef __bf16 bf16x8 __attribute__((ext_vector_type(8)));
typedef float  f32x4  __attribute__((ext_vector_type(4)));
typedef _Float16 half8v __attribute__((ext_vector_type(8)));
typedef unsigned short ushort8v __attribute__((ext_vector_type(8)));

// ---------------- fp32 -> bf16 hi/lo split (RNE both halves) ----------------
__device__ __forceinline__ void split_f32(float a, unsigned short& hi, unsigned short& lo) {
    unsigned int u = __float_as_uint(a);
    unsigned int rh = (u + 0x7fffu + ((u >> 16) & 1u)) & 0xffff0000u;
    hi = (unsigned short)(rh >> 16);
    float l = a - __uint_as_float(rh);
    unsigned int ul = __float_as_uint(l);
    lo = (unsigned short)((ul + 0x7fffu + ((ul >> 16) & 1u)) >> 16);
}

__device__ __forceinline__ void gload_lds16(const void* g, void* l) {
    __builtin_amdgcn_global_load_lds(
        (__attribute__((address_space(1))) void*)g,
        (__attribute__((address_space(3))) void*)l, 16, 0, 0);
}

// ---------------- prep combo: weight split x3 + degree count (wide flat grid) ----------------
__global__ __launch_bounds__(256) void prep_kernel(
    const float* __restrict__ W1, const float* __restrict__ W2, const float* __restrict__ W3,
    unsigned short* __restrict__ h1, unsigned short* __restrict__ l1,
    unsigned short* __restrict__ h2, unsigned short* __restrict__ l2,
    unsigned short* __restrict__ h3, unsigned short* __restrict__ l3,
    const int* __restrict__ dst, int* __restrict__ cnt)
{
    int b = blockIdx.x, t = threadIdx.x;
    if (b < 640) {
        const float* W; unsigned short *oh, *ol; int n, K, N, Kp;
        if (b < 128)      { W = W1; oh = h1; ol = l1; n = b;       K = 78;  N = 78;  Kp = 96;  }
        else if (b < 320) { W = W2; oh = h2; ol = l2; n = b - 128; K = 78;  N = 156; Kp = 96;  }
        else              { W = W3; oh = h3; ol = l3; n = b - 320; K = 156; N = 312; Kp = 160; }
        if (t < Kp) {
            float v = (n < N && t < K) ? W[(size_t)t * N + n] : 0.0f;
            unsigned short h, l;
            split_f32(v, h, l);
            oh[(size_t)n * Kp + t] = h;
            ol[(size_t)n * Kp + t] = l;
        }
    } else {
        int i = (b - 640) * 256 + t;
        if (i < EDGES) atomicAdd(&cnt[dst[i]], 1);
    }
}

// ---------------- hierarchical scan (3 wide kernels — proven fast) ----------------
__global__ __launch_bounds__(256) void scan_bsum_kernel(const int* __restrict__ cnt,
                                                        int* __restrict__ bsum, int n) {
    __shared__ int buf[256];
    int t = threadIdx.x;
    int i = blockIdx.x * 256 + t;
    buf[t] = (i < n) ? cnt[i] : 0;
    __syncthreads();
    for (int ofs = 128; ofs > 0; ofs >>= 1) {
        if (t < ofs) buf[t] += buf[t + ofs];
        __syncthreads();
    }
    if (t == 0) bsum[blockIdx.x] = buf[0];
}

__global__ __launch_bounds__(128) void scan_top_kernel(const int* __restrict__ bsum,
                                                       int* __restrict__ boff) {
    __shared__ int buf[128];
    int t = threadIdx.x;
    int own = (t < NB) ? bsum[t] : 0;
    buf[t] = own;
    __syncthreads();
    for (int ofs = 1; ofs < 128; ofs <<= 1) {
        int v = (t >= ofs) ? buf[t - ofs] : 0;
        __syncthreads();
        buf[t] += v;
        __syncthreads();
    }
    if (t < NB) boff[t] = buf[t] - own;
}

__global__ __launch_bounds__(256) void scan_apply_kernel(const int* __restrict__ cnt,
                                                         const int* __restrict__ boff,
                                                         int* __restrict__ rowstart,
                                                         int* __restrict__ cursor,
                                                         float* __restrict__ dinv, int n) {
    __shared__ int buf[256];
    int t = threadIdx.x;
    int i = blockIdx.x * 256 + t;
    int own = (i < n) ? cnt[i] : 0;
    buf[t] = own;
    __syncthreads();
    for (int ofs = 1; ofs < 256; ofs <<= 1) {
        int v = (t >= ofs) ? buf[t - ofs] : 0;
        __syncthreads();
        buf[t] += v;
        __syncthreads();
    }
    if (i < n) {
        rowstart[i] = boff[blockIdx.x] + buf[t] - own;
        cursor[i] = 0;
        dinv[i] = rsqrtf((float)own + 1.0f);
    }
}

// ---------------- fill + prescale combo (wide flat grid); prescale emits fp16 ----------------
__global__ __launch_bounds__(256) void fill_prescale_kernel(
    const int* __restrict__ src, const int* __restrict__ dst,
    const int* __restrict__ rowstart, int* __restrict__ cursor, int* __restrict__ csr_src,
    const float* __restrict__ X, const float* __restrict__ dinv,
    unsigned short* __restrict__ Xs16)
{
    int b = blockIdx.x, t = threadIdx.x;
    if (b < 1875) {
        int i = b * 256 + t;
        if (i < EDGES) {
            int d = dst[i];
            int pos = atomicAdd(&cursor[d], 1);
            csr_src[rowstart[d] + pos] = src[i];
        }
    } else {
        int i = (b - 1875) * 256 + t;
        if (i < NODES * 80) {
            int node = i / 80;
            int c = i - node * 80;
            float v = (c < 78) ? X[node * 78 + c] * dinv[node] : 0.0f;
            _Float16 hv = (_Float16)v;
            Xs16[i] = __builtin_bit_cast(unsigned short, hv);
        }
    }
}

// ---------------- aggregation from fp16 activations (all 3 layers) ----------------
template <int DVH, int KQH>
__global__ __launch_bounds__(256) void agg_half(
    const unsigned short* __restrict__ Xh, const int* __restrict__ rowstart,
    const int* __restrict__ cnt, const int* __restrict__ csr_src,
    const float* __restrict__ dinv,
    unsigned short* __restrict__ ohi, unsigned short* __restrict__ olo)
{
    constexpr int EPI = 64 / DVH;
    constexpr int Kp = KQH * 8;
    static_assert(EPI > 1, "EPI must exceed 1");
    int node = blockIdx.x * 4 + (threadIdx.x >> 6);
    int lane = threadIdx.x & 63;
    int sub = lane / DVH;
    int c = lane - sub * DVH;
    const half8v* X8 = (const half8v*)Xh;

    float acc0[8] = {}, acc1[8] = {};
    int s = rowstart[node];
    int e = s + cnt[node];

    if (sub < EPI) {
        if (sub == 0) {
            half8v v = X8[(size_t)node * DVH + c];
            #pragma unroll
            for (int i = 0; i < 8; i++) acc0[i] += (float)v[i];
        }
        int j = s;
        for (; j + 4 * EPI <= e; j += 4 * EPI) {     // 4 x 16B loads in flight / lane
            int i0 = csr_src[j + sub],           i1 = csr_src[j + EPI + sub];
            int i2 = csr_src[j + 2 * EPI + sub], i3 = csr_src[j + 3 * EPI + sub];
            half8v x0 = X8[(size_t)i0 * DVH + c], x1 = X8[(size_t)i1 * DVH + c];
            half8v x2 = X8[(size_t)i2 * DVH + c], x3 = X8[(size_t)i3 * DVH + c];
            #pragma unroll
            for (int i = 0; i < 8; i++) {
                acc0[i] += (float)x0[i] + (float)x2[i];
                acc1[i] += (float)x1[i] + (float)x3[i];
            }
        }
        for (; j + 2 * EPI <= e; j += 2 * EPI) {
            int i0 = csr_src[j + sub], i1 = csr_src[j + EPI + sub];
            half8v x0 = X8[(size_t)i0 * DVH + c], x1 = X8[(size_t)i1 * DVH + c];
            #pragma unroll
            for (int i = 0; i < 8; i++) { acc0[i] += (float)x0[i]; acc1[i] += (float)x1[i]; }
        }
        for (; j < e; j += EPI) {
            int jj = j + sub;
            if (jj < e) {
                half8v x = X8[(size_t)csr_src[jj] * DVH + c];
                #pragma unroll
                for (int i = 0; i < 8; i++) acc0[i] += (float)x[i];
            }
        }
    }
    float acc[8];
    #pragma unroll
    for (int i = 0; i < 8; i++) acc[i] = acc0[i] + acc1[i];

    // cross-subgroup reduce: read all sources first (no wrap for consumer lanes)
    {
        float tmp[EPI - 1][8];
        #pragma unroll
        for (int sft = 1; sft < EPI; sft++)
            #pragma unroll
            for (int i = 0; i < 8; i++)
                tmp[sft - 1][i] = __shfl(acc[i], lane + sft * DVH);
        #pragma unroll
        for (int sft = 1; sft < EPI; sft++)
            #pragma unroll
            for (int i = 0; i < 8; i++)
                acc[i] += tmp[sft - 1][i];
    }

    if (lane < KQH) {
        float di = (lane < DVH) ? dinv[node] : 0.0f;  // pad lanes -> exact zeros
        ushort8v h8, l8;
        #pragma unroll
        for (int i = 0; i < 8; i++) {
            unsigned short hh, ll;
            split_f32(acc[i] * di, hh, ll);
            h8[i] = hh; l8[i] = ll;
        }
        size_t off = (size_t)node * Kp + (size_t)lane * 8;
        *(ushort8v*)&ohi[off] = h8;
        *(ushort8v*)&olo[off] = l8;
    }
}

// ---------------- split-bf16 MFMA GEMM: row-persistent, in-kernel column loop ----------------
// OUT16: epilogue stores fp16 (RNE) instead of fp32.
template <int NCK, int OUT16>
__global__ __launch_bounds__(256) void mfma_gemm_v2(
    const unsigned short* __restrict__ Ahi, const unsigned short* __restrict__ Alo,
    const unsigned short* __restrict__ Bhi, const unsigned short* __restrict__ Blo,
    const float* __restrict__ bias, const float* __restrict__ scale,
    float* __restrict__ C, int M, int N, int Cstride, int nN, int do_relu)
{
    constexpr int Kp = NCK * 32;
    constexpr int CELLS = NCK * 256;
    extern __shared__ unsigned short smem[];
    unsigned short* sA = smem;
    unsigned short* sB = smem + 2 * CELLS * 8;

    int t = threadIdx.x;
    int wv = t >> 6, ln = t & 63;
    int q = ln >> 4, l16 = ln & 15;
    int wm = wv & 1, wn = wv >> 1;
    int m0 = blockIdx.x * 64;

    #pragma unroll
    for (int i = 0; i < 2 * NCK; i++) {
        int c = i * 256 + t;
        int plane = c / CELLS;
        int r = c - plane * CELLS;
        int ck = r >> 8, qq = (r >> 6) & 3, row = r & 63;
        const unsigned short* src = (plane ? Alo : Ahi) + (size_t)(m0 + row) * Kp + ck * 32 + qq * 8;
        gload_lds16(src, &sA[(size_t)c * 8]);
    }

    for (int nt = 0; nt < nN; nt++) {
        int n0 = nt * 64;
        if (nt > 0) __syncthreads();
        #pragma unroll
        for (int i = 0; i < 2 * NCK; i++) {
            int c = i * 256 + t;
            int plane = c / CELLS;
            int r = c - plane * CELLS;
            int ck = r >> 8, qq = (r >> 6) & 3, row = r & 63;
            const unsigned short* src = (plane ? Blo : Bhi) + (size_t)(n0 + row) * Kp + ck * 32 + qq * 8;
            gload_lds16(src, &sB[(size_t)c * 8]);
        }
        __syncthreads();

        f32x4 acc[2][2] = {};
        #pragma unroll
        for (int ck = 0; ck < NCK; ck++) {
            bf16x8 ah[2], al[2], bh[2], bl[2];
            #pragma unroll
            for (int i = 0; i < 2; i++) {
                int ra = wm * 32 + i * 16 + l16;
                int rb = wn * 32 + i * 16 + l16;
                ah[i] = *(const bf16x8*)&sA[(size_t)(((0 * NCK + ck) * 4 + q) * 64 + ra) * 8];
                al[i] = *(const bf16x8*)&sA[(size_t)(((1 * NCK + ck) * 4 + q) * 64 + ra) * 8];
                bh[i] = *(const bf16x8*)&sB[(size_t)(((0 * NCK + ck) * 4 + q) * 64 + rb) * 8];
                bl[i] = *(const bf16x8*)&sB[(size_t)(((1 * NCK + ck) * 4 + q) * 64 + rb) * 8];
            }
            #pragma unroll
            for (int i = 0; i < 2; i++)
                #pragma unroll
                for (int j = 0; j < 2; j++) {
                    acc[i][j] = __builtin_amdgcn_mfma_f32_16x16x32_bf16(ah[i], bh[j], acc[i][j], 0, 0, 0);
                    acc[i][j] = __builtin_amdgcn_mfma_f32_16x16x32_bf16(ah[i], bl[j], acc[i][j], 0, 0, 0);
                    acc[i][j] = __builtin_amdgcn_mfma_f32_16x16x32_bf16(al[i], bh[j], acc[i][j], 0, 0, 0);
                }
        }

        #pragma unroll
        for (int i = 0; i < 2; i++) {
            int rbase = m0 + wm * 32 + i * 16 + q * 4;
            #pragma unroll
            for (int j = 0; j < 2; j++) {
                int col = n0 + wn * 32 + j * 16 + l16;
                if (col >= Cstride) continue;
                float bv = (col < N) ? bias[col] : 0.0f;
                #pragma unroll
                for (int r = 0; r < 4; r++) {
                    int row = rbase + r;
                    if (row < M) {
                        float v = 0.0f;
                        if (col < N) {
                            v = acc[i][j][r] + bv;
                            if (do_relu) v = fmaxf(v, 0.0f);
                            if (scale) v *= scale[row];
                        }
                        if constexpr (OUT16) {
                            _Float16 hv = (_Float16)v;
                            ((unsigned short*)C)[(size_t)row * Cstride + col] =
                                __builtin_bit_cast(unsigned short, hv);
                        } else {
                            C[(size_t)row * Cstride + col] = v;
                        }
                    }
                }
            }
        }
    }
}

// ---------------- segment-max pool over fp16 H (row = 312 halves = 39 ushort8) ----------------
__device__ inline int lower_bound_dev(const int* a, int n, int v) {
    int lo = 0, hi = n;
    while (lo < hi) { int mid = (lo + hi) >> 1; if (a[mid] < v) lo = mid + 1; else hi = mid; }
    return lo;
}

__global__ __launch_bounds__(256) void pool_h16_kernel(const unsigned short* __restrict__ H,
                                                       const int* __restrict__ batch,
                                                       float* __restrict__ pooled, int n, int G) {
    __shared__ float red[6][39][8];
    int g = blockIdx.x;
    int t = threadIdx.x;
    int s = lower_bound_dev(batch, n, g);
    int e = lower_bound_dev(batch, n, g + 1);
    int rg = t / 39, c = t - rg * 39;       // 6 row-groups x 39 col-units (234 active)
    const half8v* H8 = (const half8v*)H;    // row stride = 39 units
    if (rg < 6) {
        float m[8] = {0.f, 0.f, 0.f, 0.f, 0.f, 0.f, 0.f, 0.f};
        for (int i = s + rg; i < e; i += 6) {
            half8v v = H8[(size_t)i * 39 + c];
            #pragma unroll
            for (int j = 0; j < 8; j++) m[j] = fmaxf(m[j], (float)v[j]);
        }
        #pragma unroll
        for (int j = 0; j < 8; j++) red[rg][c][j] = m[j];
    }
    __syncthreads();
    if (t < 39) {
        float m[8];
        #pragma unroll
        for (int j = 0; j < 8; j++) m[j] = red[0][t][j];
        #pragma unroll
        for (int r = 1; r < 6; r++)
            #pragma unroll
            for (int j = 0; j < 8; j++) m[j] = fmaxf(m[j], red[r][t][j]);
        float4 a = {m[0], m[1], m[2], m[3]};
        float4 b = {m[4], m[5], m[6], m[7]};
        ((float4*)pooled)[(size_t)g * 78 + t * 2]     = a;
        ((float4*)pooled)[(size_t)g * 78 + t * 2 + 1] = b;
    }
}

// ---------------- FC1: grid (4 col-tiles, 125 graph-tiles); thread = 1 col x 4 graphs ----------------
__global__ __launch_bounds__(256) void fc1_kernel(const float* __restrict__ pooled,
                                                  const float* __restrict__ Wf1,
                                                  const float* __restrict__ bf1,
                                                  float* __restrict__ f1buf) {
    __shared__ float pl[4][312];
    int cb = blockIdx.x, gb = blockIdx.y;
    int t = threadIdx.x;
    for (int i = t; i < 4 * 312; i += 256) {
        int g = i / 312, k = i - g * 312;
        pl[g][k] = pooled[(size_t)(gb * 4 + g) * 312 + k];
    }
    __syncthreads();
    int col = cb * 256 + t;
    float a0 = 0.f, a1 = 0.f, a2 = 0.f, a3 = 0.f;
    #pragma unroll 4
    for (int k = 0; k < 312; k++) {
        float w = Wf1[(size_t)k * 1024 + col];
        a0 += pl[0][k] * w; a1 += pl[1][k] * w; a2 += pl[2][k] * w; a3 += pl[3][k] * w;
    }
    float b = bf1[col];
    int g0 = gb * 4;
    f1buf[(size_t)g0 * 1024 + col]       = fmaxf(a0 + b, 0.f);
    f1buf[(size_t)(g0 + 1) * 1024 + col] = fmaxf(a1 + b, 0.f);
    f1buf[(size_t)(g0 + 2) * 1024 + col] = fmaxf(a2 + b, 0.f);
    f1buf[(size_t)(g0 + 3) * 1024 + col] = fmaxf(a3 + b, 0.f);
}

// ---------------- FC2 single dispatch: 125 blocks x 512 thr, K=1024 in 4 slices + LDS reduce ----------------
__global__ __launch_bounds__(512) void fc2_kernel(
    const float* __restrict__ f1buf, const float* __restrict__ Wf2,
    const float* __restrict__ bf2, float* __restrict__ out)
{
    __shared__ float f1s[4][1024];
    __shared__ float red[4][128][4];
    int gb = blockIdx.x;
    int t = threadIdx.x;
    const float4* F4 = (const float4*)(f1buf + (size_t)gb * 4 * 1024);
    #pragma unroll
    for (int i = 0; i < 2; i++) {
        int idx = i * 512 + t;               // [0,1024)
        ((float4*)f1s)[idx] = F4[idx];
    }
    __syncthreads();
    int col = t & 127, ks = t >> 7;          // 4 k-slices of 256
    float a0 = 0.f, a1 = 0.f, a2 = 0.f, a3 = 0.f;
    const float* w2 = Wf2 + (size_t)(ks * 256) * 128 + col;
    #pragma unroll 4
    for (int k = 0; k < 256; k++) {
        float w = w2[(size_t)k * 128];
        int kk = ks * 256 + k;
        a0 += f1s[0][kk] * w; a1 += f1s[1][kk] * w;
        a2 += f1s[2][kk] * w; a3 += f1s[3][kk] * w;
    }
    red[ks][col][0] = a0; red[ks][col][1] = a1;
    red[ks][col][2] = a2; red[ks][col][3] = a3;
    __syncthreads();
    if (t < 128) {
        float b = bf2[t];
        #pragma unroll
        for (int g = 0; g < 4; g++) {
            float s = b + red[0][t][g] + red[1][t][g] + red[2][t][g] + red[3][t][g];
            out[(size_t)(gb * 4 + g) * 128 + t] = s;
        }
    }
}

extern "C" void kernel_launch(void* const* d_in, const int* in_sizes, int n_in,
                              void* d_out, int out_size, void* d_ws, size_t ws_size,
                              hipStream_t stream) {
    const float* x    = (const float*)d_in[0];
    const int*   ei   = (const int*)d_in[1];
    const int*   batch= (const int*)d_in[2];
    const float* W1 = (const float*)d_in[3];  const float* b1  = (const float*)d_in[4];
    const float* W2 = (const float*)d_in[5];  const float* b2  = (const float*)d_in[6];
    const float* W3 = (const float*)d_in[7];  const float* b3  = (const float*)d_in[8];
    const float* Wf1= (const float*)d_in[9];  const float* bf1 = (const float*)d_in[10];
    const float* Wf2= (const float*)d_in[11]; const float* bf2 = (const float*)d_in[12];
    float* out = (float*)d_out;

    const int* srcp = ei;
    const int* dstp = ei + EDGES;

    char* p = (char*)d_ws;
    size_t o = 0;
    auto takeB = [&](size_t bytes) { char* q = p + o; o += (bytes + 255) & ~(size_t)255; return q; };
    int*   cnt      = (int*)takeB(NODES * 4);
    int*   cursor   = (int*)takeB(NODES * 4);
    int*   rowstart = (int*)takeB(NODES * 4);
    int*   bsum     = (int*)takeB(NB * 4);
    int*   boff     = (int*)takeB(NB * 4);
    float* dinv     = (float*)takeB(NODES * 4);
    int*   csr_src  = (int*)takeB(EDGES * 4);
    unsigned short* aggH = (unsigned short*)takeB((size_t)MPAD * 160 * 2);
    unsigned short* aggL = (unsigned short*)takeB((size_t)MPAD * 160 * 2);
    unsigned short* xs16 = (unsigned short*)takeB((size_t)MPAD * 80 * 2);    // fp16 prescaled input
    unsigned short* h16_1 = (unsigned short*)takeB((size_t)MPAD * 80 * 2);   // layer-1 out (fp16)
    unsigned short* h16_2 = (unsigned short*)takeB((size_t)MPAD * 160 * 2);  // layer-2 out (fp16)
    unsigned short* h16_3 = (unsigned short*)takeB((size_t)NODES * 312 * 2); // layer-3 out (fp16)
    float* pooled  = (float*)takeB((size_t)GRAPHS * 312 * 4);
    float* f1buf   = (float*)takeB((size_t)GRAPHS * 1024 * 4);
    unsigned short* Wt1h = (unsigned short*)takeB(128 * 96 * 2);
    unsigned short* Wt1l = (unsigned short*)takeB(128 * 96 * 2);
    unsigned short* Wt2h = (unsigned short*)takeB(192 * 96 * 2);
    unsigned short* Wt2l = (unsigned short*)takeB(192 * 96 * 2);
    unsigned short* Wt3h = (unsigned short*)takeB(320 * 160 * 2);
    unsigned short* Wt3l = (unsigned short*)takeB(320 * 160 * 2);
    (void)ws_size;

    hipMemsetAsync(cnt, 0, NODES * sizeof(int), stream);

    // prep: wsplit x3 + count in one wide dispatch
    prep_kernel<<<640 + 1875, 256, 0, stream>>>(W1, W2, W3, Wt1h, Wt1l, Wt2h, Wt2l,
                                                Wt3h, Wt3l, dstp, cnt);
    // hierarchical scan (cursor zeroed in scan_apply)
    scan_bsum_kernel<<<NB, 256, 0, stream>>>(cnt, bsum, NODES);
    scan_top_kernel<<<1, 128, 0, stream>>>(bsum, boff);
    scan_apply_kernel<<<NB, 256, 0, stream>>>(cnt, boff, rowstart, cursor, dinv, NODES);
    // fill + prescale (fp16) in one wide dispatch
    fill_prescale_kernel<<<1875 + 9375, 256, 0, stream>>>(srcp, dstp, rowstart, cursor,
                                                          csr_src, x, dinv, xs16);

    const int NBLK = MPAD / 64;   // 469
    const int AGRID = NODES / 4;  // 7500

    // layer 1: fp16 gather from xs16 (row 160 B, WS 4.8 MB) -> GEMM writes fp16 h16_1
    agg_half<10, 12><<<AGRID, 256, 0, stream>>>(xs16, rowstart, cnt, csr_src, dinv, aggH, aggL);
    mfma_gemm_v2<3, 1><<<NBLK, 256, 3 * 16384, stream>>>(aggH, aggL, Wt1h, Wt1l, b1, dinv,
                                                         (float*)h16_1, NODES, 78, 80, 2, 1);
    // layer 2: fp16 gather (row 160 B, WS 4.8 MB) -> GEMM writes fp16 h16_2 (stride 160)
    agg_half<10, 12><<<AGRID, 256, 0, stream>>>(h16_1, rowstart, cnt, csr_src, dinv, aggH, aggL);
    mfma_gemm_v2<3, 1><<<NBLK, 256, 3 * 16384, stream>>>(aggH, aggL, Wt2h, Wt2l, b2, dinv,
                                                         (float*)h16_2, NODES, 156, 160, 3, 1);
    // layer 3: fp16 gather (row 320 B, WS 9.6 MB) -> GEMM writes fp16 h16_3 (stride 312) for pooling
    agg_half<20, 20><<<AGRID, 256, 0, stream>>>(h16_2, rowstart, cnt, csr_src, dinv, aggH, aggL);
    mfma_gemm_v2<5, 1><<<NBLK, 256, 5 * 16384, stream>>>(aggH, aggL, Wt3h, Wt3l, b3, nullptr,
                                                         (float*)h16_3, NODES, 312, 312, 5, 1);

    pool_h16_kernel<<<GRAPHS, 256, 0, stream>>>(h16_3, batch, pooled, NODES, GRAPHS);
    fc1_kernel<<<dim3(4, GRAPHS / 4), 256, 0, stream>>>(pooled, Wf1, bf1, f1buf);
    fc2_kernel<<<GRAPHS / 4, 512, 0, stream>>>(f1buf, Wf2, bf2, out);
}

// Round 10
// 313.926 us; speedup vs baseline: 1.0174x; 1.0174x over previous
//
#include <hip/hip_runtime.h>

#define NODES  30000
#define EDGES  480000
#define GRAPHS 500
#define MPAD   30016   // 64*469
#define NB     118     // scan blocks: ceil(30000/256)

typedef __bf16 bf16x8 __attribute__((ext_vector_type(8)));
typedef float  f32x4  __attribute__((ext_vector_type(4)));
typedef _Float16 half8v __attribute__((ext_vector_type(8)));
typedef unsigned short ushort8v __attribute__((ext_vector_type(8)));

__device__ __forceinline__ float4 f4max(float4 a, float4 b) {
    a.x = fmaxf(a.x, b.x); a.y = fmaxf(a.y, b.y);
    a.z = fmaxf(a.z, b.z); a.w = fmaxf(a.w, b.w); return a;
}

// ---------------- fp32 -> bf16 hi/lo split (RNE both halves) ----------------
__device__ __forceinline__ void split_f32(float a, unsigned short& hi, unsigned short& lo) {
    unsigned int u = __float_as_uint(a);
    unsigned int rh = (u + 0x7fffu + ((u >> 16) & 1u)) & 0xffff0000u;
    hi = (unsigned short)(rh >> 16);
    float l = a - __uint_as_float(rh);
    unsigned int ul = __float_as_uint(l);
    lo = (unsigned short)((ul + 0x7fffu + ((ul >> 16) & 1u)) >> 16);
}

__device__ __forceinline__ void gload_lds16(const void* g, void* l) {
    __builtin_amdgcn_global_load_lds(
        (__attribute__((address_space(1))) void*)g,
        (__attribute__((address_space(3))) void*)l, 16, 0, 0);
}

// ---------------- prep combo: weight split x3 + degree count (wide flat grid) ----------------
__global__ __launch_bounds__(256) void prep_kernel(
    const float* __restrict__ W1, const float* __restrict__ W2, const float* __restrict__ W3,
    unsigned short* __restrict__ h1, unsigned short* __restrict__ l1,
    unsigned short* __restrict__ h2, unsigned short* __restrict__ l2,
    unsigned short* __restrict__ h3, unsigned short* __restrict__ l3,
    const int* __restrict__ dst, int* __restrict__ cnt)
{
    int b = blockIdx.x, t = threadIdx.x;
    if (b < 640) {
        const float* W; unsigned short *oh, *ol; int n, K, N, Kp;
        if (b < 128)      { W = W1; oh = h1; ol = l1; n = b;       K = 78;  N = 78;  Kp = 96;  }
        else if (b < 320) { W = W2; oh = h2; ol = l2; n = b - 128; K = 78;  N = 156; Kp = 96;  }
        else              { W = W3; oh = h3; ol = l3; n = b - 320; K = 156; N = 312; Kp = 160; }
        if (t < Kp) {
            float v = (n < N && t < K) ? W[(size_t)t * N + n] : 0.0f;
            unsigned short h, l;
            split_f32(v, h, l);
            oh[(size_t)n * Kp + t] = h;
            ol[(size_t)n * Kp + t] = l;
        }
    } else {
        int i = (b - 640) * 256 + t;
        if (i < EDGES) atomicAdd(&cnt[dst[i]], 1);
    }
}

// ---------------- hierarchical scan (3 wide kernels — proven fast) ----------------
__global__ __launch_bounds__(256) void scan_bsum_kernel(const int* __restrict__ cnt,
                                                        int* __restrict__ bsum, int n) {
    __shared__ int buf[256];
    int t = threadIdx.x;
    int i = blockIdx.x * 256 + t;
    buf[t] = (i < n) ? cnt[i] : 0;
    __syncthreads();
    for (int ofs = 128; ofs > 0; ofs >>= 1) {
        if (t < ofs) buf[t] += buf[t + ofs];
        __syncthreads();
    }
    if (t == 0) bsum[blockIdx.x] = buf[0];
}

__global__ __launch_bounds__(128) void scan_top_kernel(const int* __restrict__ bsum,
                                                       int* __restrict__ boff) {
    __shared__ int buf[128];
    int t = threadIdx.x;
    int own = (t < NB) ? bsum[t] : 0;
    buf[t] = own;
    __syncthreads();
    for (int ofs = 1; ofs < 128; ofs <<= 1) {
        int v = (t >= ofs) ? buf[t - ofs] : 0;
        __syncthreads();
        buf[t] += v;
        __syncthreads();
    }
    if (t < NB) boff[t] = buf[t] - own;
}

__global__ __launch_bounds__(256) void scan_apply_kernel(const int* __restrict__ cnt,
                                                         const int* __restrict__ boff,
                                                         int* __restrict__ rowstart,
                                                         int* __restrict__ cursor,
                                                         float* __restrict__ dinv, int n) {
    __shared__ int buf[256];
    int t = threadIdx.x;
    int i = blockIdx.x * 256 + t;
    int own = (i < n) ? cnt[i] : 0;
    buf[t] = own;
    __syncthreads();
    for (int ofs = 1; ofs < 256; ofs <<= 1) {
        int v = (t >= ofs) ? buf[t - ofs] : 0;
        __syncthreads();
        buf[t] += v;
        __syncthreads();
    }
    if (i < n) {
        rowstart[i] = boff[blockIdx.x] + buf[t] - own;
        cursor[i] = 0;
        dinv[i] = rsqrtf((float)own + 1.0f);
    }
}

// ---------------- fill + prescale combo (wide flat grid); prescale emits fp16 ----------------
__global__ __launch_bounds__(256) void fill_prescale_kernel(
    const int* __restrict__ src, const int* __restrict__ dst,
    const int* __restrict__ rowstart, int* __restrict__ cursor, int* __restrict__ csr_src,
    const float* __restrict__ X, const float* __restrict__ dinv,
    unsigned short* __restrict__ Xs16)
{
    int b = blockIdx.x, t = threadIdx.x;
    if (b < 1875) {
        int i = b * 256 + t;
        if (i < EDGES) {
            int d = dst[i];
            int pos = atomicAdd(&cursor[d], 1);
            csr_src[rowstart[d] + pos] = src[i];
        }
    } else {
        int i = (b - 1875) * 256 + t;
        if (i < NODES * 80) {
            int node = i / 80;
            int c = i - node * 80;
            float v = (c < 78) ? X[node * 78 + c] * dinv[node] : 0.0f;
            _Float16 hv = (_Float16)v;
            Xs16[i] = __builtin_bit_cast(unsigned short, hv);
        }
    }
}

// ---------------- aggregation from fp16 activations (all 3 layers) ----------------
template <int DVH, int KQH>
__global__ __launch_bounds__(256) void agg_half(
    const unsigned short* __restrict__ Xh, const int* __restrict__ rowstart,
    const int* __restrict__ cnt, const int* __restrict__ csr_src,
    const float* __restrict__ dinv,
    unsigned short* __restrict__ ohi, unsigned short* __restrict__ olo)
{
    constexpr int EPI = 64 / DVH;
    constexpr int Kp = KQH * 8;
    static_assert(EPI > 1, "EPI must exceed 1");
    int node = blockIdx.x * 4 + (threadIdx.x >> 6);
    int lane = threadIdx.x & 63;
    int sub = lane / DVH;
    int c = lane - sub * DVH;
    const half8v* X8 = (const half8v*)Xh;

    float acc0[8] = {}, acc1[8] = {};
    int s = rowstart[node];
    int e = s + cnt[node];

    if (sub < EPI) {
        if (sub == 0) {
            half8v v = X8[(size_t)node * DVH + c];
            #pragma unroll
            for (int i = 0; i < 8; i++) acc0[i] += (float)v[i];
        }
        int j = s;
        for (; j + 4 * EPI <= e; j += 4 * EPI) {     // 4 x 16B loads in flight / lane
            int i0 = csr_src[j + sub],           i1 = csr_src[j + EPI + sub];
            int i2 = csr_src[j + 2 * EPI + sub], i3 = csr_src[j + 3 * EPI + sub];
            half8v x0 = X8[(size_t)i0 * DVH + c], x1 = X8[(size_t)i1 * DVH + c];
            half8v x2 = X8[(size_t)i2 * DVH + c], x3 = X8[(size_t)i3 * DVH + c];
            #pragma unroll
            for (int i = 0; i < 8; i++) {
                acc0[i] += (float)x0[i] + (float)x2[i];
                acc1[i] += (float)x1[i] + (float)x3[i];
            }
        }
        for (; j + 2 * EPI <= e; j += 2 * EPI) {
            int i0 = csr_src[j + sub], i1 = csr_src[j + EPI + sub];
            half8v x0 = X8[(size_t)i0 * DVH + c], x1 = X8[(size_t)i1 * DVH + c];
            #pragma unroll
            for (int i = 0; i < 8; i++) { acc0[i] += (float)x0[i]; acc1[i] += (float)x1[i]; }
        }
        for (; j < e; j += EPI) {
            int jj = j + sub;
            if (jj < e) {
                half8v x = X8[(size_t)csr_src[jj] * DVH + c];
                #pragma unroll
                for (int i = 0; i < 8; i++) acc0[i] += (float)x[i];
            }
        }
    }
    float acc[8];
    #pragma unroll
    for (int i = 0; i < 8; i++) acc[i] = acc0[i] + acc1[i];

    // cross-subgroup reduce: read all sources first (no wrap for consumer lanes)
    {
        float tmp[EPI - 1][8];
        #pragma unroll
        for (int sft = 1; sft < EPI; sft++)
            #pragma unroll
            for (int i = 0; i < 8; i++)
                tmp[sft - 1][i] = __shfl(acc[i], lane + sft * DVH);
        #pragma unroll
        for (int sft = 1; sft < EPI; sft++)
            #pragma unroll
            for (int i = 0; i < 8; i++)
                acc[i] += tmp[sft - 1][i];
    }

    if (lane < KQH) {
        float di = (lane < DVH) ? dinv[node] : 0.0f;  // pad lanes -> exact zeros
        ushort8v h8, l8;
        #pragma unroll
        for (int i = 0; i < 8; i++) {
            unsigned short hh, ll;
            split_f32(acc[i] * di, hh, ll);
            h8[i] = hh; l8[i] = ll;
        }
        size_t off = (size_t)node * Kp + (size_t)lane * 8;
        *(ushort8v*)&ohi[off] = h8;
        *(ushort8v*)&olo[off] = l8;
    }
}

// ---------------- split-bf16 MFMA GEMM: row-persistent, in-kernel column loop ----------------
// OUT16: epilogue stores fp16 (RNE) instead of fp32 (for inter-layer activations).
template <int NCK, int OUT16>
__global__ __launch_bounds__(256) void mfma_gemm_v2(
    const unsigned short* __restrict__ Ahi, const unsigned short* __restrict__ Alo,
    const unsigned short* __restrict__ Bhi, const unsigned short* __restrict__ Blo,
    const float* __restrict__ bias, const float* __restrict__ scale,
    float* __restrict__ C, int M, int N, int Cstride, int nN, int do_relu)
{
    constexpr int Kp = NCK * 32;
    constexpr int CELLS = NCK * 256;
    extern __shared__ unsigned short smem[];
    unsigned short* sA = smem;
    unsigned short* sB = smem + 2 * CELLS * 8;

    int t = threadIdx.x;
    int wv = t >> 6, ln = t & 63;
    int q = ln >> 4, l16 = ln & 15;
    int wm = wv & 1, wn = wv >> 1;
    int m0 = blockIdx.x * 64;

    #pragma unroll
    for (int i = 0; i < 2 * NCK; i++) {
        int c = i * 256 + t;
        int plane = c / CELLS;
        int r = c - plane * CELLS;
        int ck = r >> 8, qq = (r >> 6) & 3, row = r & 63;
        const unsigned short* src = (plane ? Alo : Ahi) + (size_t)(m0 + row) * Kp + ck * 32 + qq * 8;
        gload_lds16(src, &sA[(size_t)c * 8]);
    }

    for (int nt = 0; nt < nN; nt++) {
        int n0 = nt * 64;
        if (nt > 0) __syncthreads();
        #pragma unroll
        for (int i = 0; i < 2 * NCK; i++) {
            int c = i * 256 + t;
            int plane = c / CELLS;
            int r = c - plane * CELLS;
            int ck = r >> 8, qq = (r >> 6) & 3, row = r & 63;
            const unsigned short* src = (plane ? Blo : Bhi) + (size_t)(n0 + row) * Kp + ck * 32 + qq * 8;
            gload_lds16(src, &sB[(size_t)c * 8]);
        }
        __syncthreads();

        f32x4 acc[2][2] = {};
        #pragma unroll
        for (int ck = 0; ck < NCK; ck++) {
            bf16x8 ah[2], al[2], bh[2], bl[2];
            #pragma unroll
            for (int i = 0; i < 2; i++) {
                int ra = wm * 32 + i * 16 + l16;
                int rb = wn * 32 + i * 16 + l16;
                ah[i] = *(const bf16x8*)&sA[(size_t)(((0 * NCK + ck) * 4 + q) * 64 + ra) * 8];
                al[i] = *(const bf16x8*)&sA[(size_t)(((1 * NCK + ck) * 4 + q) * 64 + ra) * 8];
                bh[i] = *(const bf16x8*)&sB[(size_t)(((0 * NCK + ck) * 4 + q) * 64 + rb) * 8];
                bl[i] = *(const bf16x8*)&sB[(size_t)(((1 * NCK + ck) * 4 + q) * 64 + rb) * 8];
            }
            #pragma unroll
            for (int i = 0; i < 2; i++)
                #pragma unroll
                for (int j = 0; j < 2; j++) {
                    acc[i][j] = __builtin_amdgcn_mfma_f32_16x16x32_bf16(ah[i], bh[j], acc[i][j], 0, 0, 0);
                    acc[i][j] = __builtin_amdgcn_mfma_f32_16x16x32_bf16(ah[i], bl[j], acc[i][j], 0, 0, 0);
                    acc[i][j] = __builtin_amdgcn_mfma_f32_16x16x32_bf16(al[i], bh[j], acc[i][j], 0, 0, 0);
                }
        }

        #pragma unroll
        for (int i = 0; i < 2; i++) {
            int rbase = m0 + wm * 32 + i * 16 + q * 4;
            #pragma unroll
            for (int j = 0; j < 2; j++) {
                int col = n0 + wn * 32 + j * 16 + l16;
                if (col >= Cstride) continue;
                float bv = (col < N) ? bias[col] : 0.0f;
                #pragma unroll
                for (int r = 0; r < 4; r++) {
                    int row = rbase + r;
                    if (row < M) {
                        float v = 0.0f;
                        if (col < N) {
                            v = acc[i][j][r] + bv;
                            if (do_relu) v = fmaxf(v, 0.0f);
                            if (scale) v *= scale[row];
                        }
                        if constexpr (OUT16) {
                            _Float16 hv = (_Float16)v;
                            ((unsigned short*)C)[(size_t)row * Cstride + col] =
                                __builtin_bit_cast(unsigned short, hv);
                        } else {
                            C[(size_t)row * Cstride + col] = v;
                        }
                    }
                }
            }
        }
    }
}

// ---------------- segment-max pool (batch sorted), 3-way row-parallel + LDS combine ----------------
__device__ inline int lower_bound_dev(const int* a, int n, int v) {
    int lo = 0, hi = n;
    while (lo < hi) { int mid = (lo + hi) >> 1; if (a[mid] < v) lo = mid + 1; else hi = mid; }
    return lo;
}

__global__ __launch_bounds__(256) void pool_kernel(const float* __restrict__ H,
                                                   const int* __restrict__ batch,
                                                   float* __restrict__ pooled, int n, int G) {
    __shared__ float4 red[3][78];
    int g = blockIdx.x;
    int t = threadIdx.x;
    int s = lower_bound_dev(batch, n, g);
    int e = lower_bound_dev(batch, n, g + 1);
    int rg = t / 78, c = t - rg * 78;
    const float4* H4 = (const float4*)H;
    if (rg < 3) {
        float4 m = {0.f, 0.f, 0.f, 0.f};
        for (int i = s + rg; i < e; i += 3)
            m = f4max(m, H4[(size_t)i * 78 + c]);
        red[rg][c] = m;
    }
    __syncthreads();
    if (t < 78) {
        float4 m = f4max(f4max(red[0][t], red[1][t]), red[2][t]);
        ((float4*)pooled)[(size_t)g * 78 + t] = m;
    }
}

// ---------------- FC1: grid (4 col-tiles, 125 graph-tiles); thread = 1 col x 4 graphs ----------------
__global__ __launch_bounds__(256) void fc1_kernel(const float* __restrict__ pooled,
                                                  const float* __restrict__ Wf1,
                                                  const float* __restrict__ bf1,
                                                  float* __restrict__ f1buf) {
    __shared__ float pl[4][312];
    int cb = blockIdx.x, gb = blockIdx.y;
    int t = threadIdx.x;
    for (int i = t; i < 4 * 312; i += 256) {
        int g = i / 312, k = i - g * 312;
        pl[g][k] = pooled[(size_t)(gb * 4 + g) * 312 + k];
    }
    __syncthreads();
    int col = cb * 256 + t;
    float a0 = 0.f, a1 = 0.f, a2 = 0.f, a3 = 0.f;
    #pragma unroll 4
    for (int k = 0; k < 312; k++) {
        float w = Wf1[(size_t)k * 1024 + col];
        a0 += pl[0][k] * w; a1 += pl[1][k] * w; a2 += pl[2][k] * w; a3 += pl[3][k] * w;
    }
    float b = bf1[col];
    int g0 = gb * 4;
    f1buf[(size_t)g0 * 1024 + col]       = fmaxf(a0 + b, 0.f);
    f1buf[(size_t)(g0 + 1) * 1024 + col] = fmaxf(a1 + b, 0.f);
    f1buf[(size_t)(g0 + 2) * 1024 + col] = fmaxf(a2 + b, 0.f);
    f1buf[(size_t)(g0 + 3) * 1024 + col] = fmaxf(a3 + b, 0.f);
}

// ---------------- FC2 k-split: grid (8 k-tiles, 125 graph-tiles); deterministic partials ----------------
__global__ __launch_bounds__(256) void fc2_part_kernel(const float* __restrict__ f1buf,
                                                       const float* __restrict__ Wf2,
                                                       float* __restrict__ partial) {
    __shared__ float f1s[4][128];
    __shared__ float red[256][4];
    int kt = blockIdx.x;
    int gb = blockIdx.y;
    int t = threadIdx.x;
    int col = t & 127, ks = t >> 7;
    for (int i = t; i < 512; i += 256) {
        int g = i >> 7, k = i & 127;
        f1s[g][k] = f1buf[(size_t)(gb * 4 + g) * 1024 + kt * 128 + k];
    }
    __syncthreads();
    float a0 = 0.f, a1 = 0.f, a2 = 0.f, a3 = 0.f;
    const float* w2 = Wf2 + (size_t)(kt * 128 + ks * 64) * 128 + col;
    #pragma unroll 4
    for (int k = 0; k < 64; k++) {
        float w = w2[(size_t)k * 128];
        int kk = ks * 64 + k;
        a0 += f1s[0][kk] * w; a1 += f1s[1][kk] * w; a2 += f1s[2][kk] * w; a3 += f1s[3][kk] * w;
    }
    red[t][0] = a0; red[t][1] = a1; red[t][2] = a2; red[t][3] = a3;
    __syncthreads();
    if (t < 128) {
        #pragma unroll
        for (int g = 0; g < 4; g++)
            partial[((size_t)kt * GRAPHS + gb * 4 + g) * 128 + col] = red[t][g] + red[t + 128][g];
    }
}

__global__ void fc2_reduce_kernel(const float* __restrict__ partial, const float* __restrict__ bf2,
                                  float* __restrict__ out, int total) {
    int i = blockIdx.x * blockDim.x + threadIdx.x;
    if (i < total) {
        float s = bf2[i & 127];
        #pragma unroll
        for (int kt = 0; kt < 8; kt++) s += partial[(size_t)kt * total + i];
        out[i] = s;
    }
}

extern "C" void kernel_launch(void* const* d_in, const int* in_sizes, int n_in,
                              void* d_out, int out_size, void* d_ws, size_t ws_size,
                              hipStream_t stream) {
    const float* x    = (const float*)d_in[0];
    const int*   ei   = (const int*)d_in[1];
    const int*   batch= (const int*)d_in[2];
    const float* W1 = (const float*)d_in[3];  const float* b1  = (const float*)d_in[4];
    const float* W2 = (const float*)d_in[5];  const float* b2  = (const float*)d_in[6];
    const float* W3 = (const float*)d_in[7];  const float* b3  = (const float*)d_in[8];
    const float* Wf1= (const float*)d_in[9];  const float* bf1 = (const float*)d_in[10];
    const float* Wf2= (const float*)d_in[11]; const float* bf2 = (const float*)d_in[12];
    float* out = (float*)d_out;

    const int* srcp = ei;
    const int* dstp = ei + EDGES;

    char* p = (char*)d_ws;
    size_t o = 0;
    auto takeB = [&](size_t bytes) { char* q = p + o; o += (bytes + 255) & ~(size_t)255; return q; };
    int*   cnt      = (int*)takeB(NODES * 4);
    int*   cursor   = (int*)takeB(NODES * 4);
    int*   rowstart = (int*)takeB(NODES * 4);
    int*   bsum     = (int*)takeB(NB * 4);
    int*   boff     = (int*)takeB(NB * 4);
    float* dinv     = (float*)takeB(NODES * 4);
    int*   csr_src  = (int*)takeB(EDGES * 4);
    unsigned short* aggH = (unsigned short*)takeB((size_t)MPAD * 160 * 2);
    unsigned short* aggL = (unsigned short*)takeB((size_t)MPAD * 160 * 2);
    unsigned short* xs16 = (unsigned short*)takeB((size_t)MPAD * 80 * 2);   // fp16 prescaled input
    float* hbuf    = (float*)takeB((size_t)NODES * 312 * 4);
    unsigned short* h16_1 = (unsigned short*)takeB((size_t)MPAD * 80 * 2);   // layer-1 out (fp16)
    unsigned short* h16_2 = (unsigned short*)takeB((size_t)MPAD * 160 * 2);  // layer-2 out (fp16)
    float* pooled  = (float*)takeB((size_t)GRAPHS * 312 * 4);
    float* f1buf   = (float*)takeB((size_t)GRAPHS * 1024 * 4);
    float* partial = (float*)takeB((size_t)8 * GRAPHS * 128 * 4);
    unsigned short* Wt1h = (unsigned short*)takeB(128 * 96 * 2);
    unsigned short* Wt1l = (unsigned short*)takeB(128 * 96 * 2);
    unsigned short* Wt2h = (unsigned short*)takeB(192 * 96 * 2);
    unsigned short* Wt2l = (unsigned short*)takeB(192 * 96 * 2);
    unsigned short* Wt3h = (unsigned short*)takeB(320 * 160 * 2);
    unsigned short* Wt3l = (unsigned short*)takeB(320 * 160 * 2);
    (void)ws_size;

    hipMemsetAsync(cnt, 0, NODES * sizeof(int), stream);

    // prep: wsplit x3 + count in one wide dispatch
    prep_kernel<<<640 + 1875, 256, 0, stream>>>(W1, W2, W3, Wt1h, Wt1l, Wt2h, Wt2l,
                                                Wt3h, Wt3l, dstp, cnt);
    // hierarchical scan (cursor zeroed in scan_apply)
    scan_bsum_kernel<<<NB, 256, 0, stream>>>(cnt, bsum, NODES);
    scan_top_kernel<<<1, 128, 0, stream>>>(bsum, boff);
    scan_apply_kernel<<<NB, 256, 0, stream>>>(cnt, boff, rowstart, cursor, dinv, NODES);
    // fill + prescale (fp16) in one wide dispatch
    fill_prescale_kernel<<<1875 + 9375, 256, 0, stream>>>(srcp, dstp, rowstart, cursor,
                                                          csr_src, x, dinv, xs16);

    const int NBLK = MPAD / 64;   // 469
    const int AGRID = NODES / 4;  // 7500

    // layer 1: fp16 gather from xs16 (row 160 B, WS 4.8 MB) -> GEMM writes fp16 h16_1
    agg_half<10, 12><<<AGRID, 256, 0, stream>>>(xs16, rowstart, cnt, csr_src, dinv, aggH, aggL);
    mfma_gemm_v2<3, 1><<<NBLK, 256, 3 * 16384, stream>>>(aggH, aggL, Wt1h, Wt1l, b1, dinv,
                                                         (float*)h16_1, NODES, 78, 80, 2, 1);
    // layer 2: fp16 gather (row 160 B, WS 4.8 MB) -> GEMM writes fp16 h16_2 (stride 160)
    agg_half<10, 12><<<AGRID, 256, 0, stream>>>(h16_1, rowstart, cnt, csr_src, dinv, aggH, aggL);
    mfma_gemm_v2<3, 1><<<NBLK, 256, 3 * 16384, stream>>>(aggH, aggL, Wt2h, Wt2l, b2, dinv,
                                                         (float*)h16_2, NODES, 156, 160, 3, 1);
    // layer 3: fp16 gather (row 320 B, WS 9.6 MB) -> GEMM writes fp32 hbuf for pooling
    agg_half<20, 20><<<AGRID, 256, 0, stream>>>(h16_2, rowstart, cnt, csr_src, dinv, aggH, aggL);
    mfma_gemm_v2<5, 0><<<NBLK, 256, 5 * 16384, stream>>>(aggH, aggL, Wt3h, Wt3l, b3, nullptr,
                                                         hbuf, NODES, 312, 312, 5, 1);

    pool_kernel<<<GRAPHS, 256, 0, stream>>>(hbuf, batch, pooled, NODES, GRAPHS);
    fc1_kernel<<<dim3(4, GRAPHS / 4), 256, 0, stream>>>(pooled, Wf1, bf1, f1buf);
    fc2_part_kernel<<<dim3(8, GRAPHS / 4), 256, 0, stream>>>(f1buf, Wf2, partial);
    fc2_reduce_kernel<<<(GRAPHS * 128 + 255) / 256, 256, 0, stream>>>(partial, bf2, out, GRAPHS * 128);
}